// Round 1
// baseline (368.526 us; speedup 1.0000x reference)
//
#include <hip/hip_runtime.h>

// ============================================================================
// Fused ViT attention block on MI355X (gfx950), all-bf16-MFMA pipeline.
//   B=4, N=2048, D=1024, H=16, Hd=64, M=B*N=8192
// Stages:
//   1) cvt x -> bf16; transpose W_qkv/W_proj -> [N][K] bf16
//   2) GEMM1: qkv[8192][3072] = xb @ WqkvT   (m97-style 128x128, BK=32)
//   3) v-transpose: vt[b,h,64,2048]
//   4) flash attention (transposed-output scheme, no block barriers)
//   5) GEMM2: out = ao @ WprojT + bias (fp32 out)
// ============================================================================

#define DEV __device__ __forceinline__

typedef __attribute__((ext_vector_type(8))) short bf16x8;
typedef __attribute__((ext_vector_type(4))) float f32x4;

DEV unsigned short f2b(float f) {
  union { float f; unsigned u; } x; x.f = f;
  unsigned r = (x.u + 0x7FFFu + ((x.u >> 16) & 1u)) >> 16;
  return (unsigned short)r;
}

DEV void gload16(const void* g, void* l) {
  __builtin_amdgcn_global_load_lds((const __attribute__((address_space(1))) void*)g,
                                   (__attribute__((address_space(3))) void*)l,
                                   16, 0, 0);
}

// ---------------------------------------------------------------------------
// fp32 -> bf16 elementwise (x)
__global__ void k_cvt(const float* __restrict__ in, unsigned short* __restrict__ out) {
  int i = (blockIdx.x * 256 + threadIdx.x) * 4;
  float4 v = *(const float4*)&in[i];
  *(ushort4*)&out[i] = make_ushort4(f2b(v.x), f2b(v.y), f2b(v.z), f2b(v.w));
}

// ---------------------------------------------------------------------------
// W[K][Nw] fp32 -> Wt[Nw][K] bf16 (LDS tile transpose)
__global__ void k_wt(const float* __restrict__ W, unsigned short* __restrict__ Wt,
                     int Nw, int K) {
  __shared__ float t[64][65];
  const int k0 = blockIdx.y * 64, n0 = blockIdx.x * 64;
  const int tx = threadIdx.x, ty = threadIdx.y;
#pragma unroll
  for (int i = 0; i < 16; ++i) {
    int r = i * 4 + ty;
    t[r][tx] = W[(size_t)(k0 + r) * Nw + n0 + tx];
  }
  __syncthreads();
#pragma unroll
  for (int i = 0; i < 16; ++i) {
    int r = i * 4 + ty;
    Wt[(size_t)(n0 + r) * K + k0 + tx] = f2b(t[tx][r]);
  }
}

// ---------------------------------------------------------------------------
// v slice of qkv -> vt[b,h,64,2048] (bf16 transpose via LDS)
__global__ void k_vt(const unsigned short* __restrict__ qkv, unsigned short* __restrict__ vt) {
  __shared__ unsigned short t[64][68];
  const int bh = blockIdx.y;
  const int b = bh >> 4, h = bh & 15;
  const int n0 = blockIdx.x * 64;
  const int tx = threadIdx.x, ty = threadIdx.y;
#pragma unroll
  for (int i = 0; i < 16; ++i) {
    int r = i * 4 + ty;
    t[r][tx] = qkv[(size_t)(b * 2048 + n0 + r) * 3072 + 2048 + h * 64 + tx];
  }
  __syncthreads();
#pragma unroll
  for (int i = 0; i < 16; ++i) {
    int d = i * 4 + ty;
    vt[(size_t)(bh * 64 + d) * 2048 + n0 + tx] = t[tx][d];
  }
}

// ---------------------------------------------------------------------------
// GEMM: C[M][N] = A[M][K] @ Bt[N][K]^T ; A,Bt bf16 row-major, k-contiguous.
// m97 structure: 128x128 tile, BK=32, 4 waves, global_load_lds width=16.
template <bool PROJ>
__global__ __launch_bounds__(256, 2) void gemm_bt(
    const unsigned short* __restrict__ A, const unsigned short* __restrict__ Bt,
    unsigned short* __restrict__ outB, float* __restrict__ outF,
    const float* __restrict__ bias, int M, int N, int K) {
  __shared__ unsigned short Al[128 * 32];
  __shared__ unsigned short Bl[128 * 32];
  const int tid = threadIdx.x;
  const int lane = tid & 63;
  const int wv = tid >> 6;
  const int m0 = blockIdx.y * 128;
  const int n0 = blockIdx.x * 128;
  const int wrow = (wv >> 1) * 64;
  const int wcol = (wv & 1) * 64;

  f32x4 acc[4][4];
#pragma unroll
  for (int i = 0; i < 4; ++i)
#pragma unroll
    for (int j = 0; j < 4; ++j) acc[i][j] = (f32x4){0.f, 0.f, 0.f, 0.f};

  const int lr = lane >> 2;        // row within 16-row staging chunk
  const int lk = (lane & 3) * 8;   // k element offset within chunk
  const int fr = lane & 15;        // fragment row/col
  const int fg = (lane >> 4) * 8;  // fragment k-group offset

  const unsigned short* gA = A + (size_t)(m0 + wv * 32 + lr) * K + lk;
  const unsigned short* gB = Bt + (size_t)(n0 + wv * 32 + lr) * K + lk;
  unsigned short* lA0 = &Al[(wv * 2 + 0) * 512];
  unsigned short* lA1 = &Al[(wv * 2 + 1) * 512];
  unsigned short* lB0 = &Bl[(wv * 2 + 0) * 512];
  unsigned short* lB1 = &Bl[(wv * 2 + 1) * 512];

  const int nk = K >> 5;
  for (int kt = 0; kt < nk; ++kt) {
    const int k0 = kt << 5;
    gload16(gA + k0, lA0);
    gload16(gA + k0 + (size_t)16 * K, lA1);
    gload16(gB + k0, lB0);
    gload16(gB + k0 + (size_t)16 * K, lB1);
    __syncthreads();
    bf16x8 af[4], bfv[4];
#pragma unroll
    for (int i = 0; i < 4; ++i) af[i] = *(const bf16x8*)&Al[(wrow + i * 16 + fr) * 32 + fg];
#pragma unroll
    for (int j = 0; j < 4; ++j) bfv[j] = *(const bf16x8*)&Bl[(wcol + j * 16 + fr) * 32 + fg];
#pragma unroll
    for (int i = 0; i < 4; ++i)
#pragma unroll
      for (int j = 0; j < 4; ++j)
        acc[i][j] = __builtin_amdgcn_mfma_f32_16x16x32_bf16(af[i], bfv[j], acc[i][j], 0, 0, 0);
    __syncthreads();
  }

  const int rg = (lane >> 4) * 4;
#pragma unroll
  for (int i = 0; i < 4; ++i) {
#pragma unroll
    for (int j = 0; j < 4; ++j) {
      const int col = n0 + wcol + j * 16 + fr;
#pragma unroll
      for (int r = 0; r < 4; ++r) {
        const int row = m0 + wrow + i * 16 + rg + r;
        if (PROJ)
          outF[(size_t)row * N + col] = acc[i][j][r] + bias[col];
        else
          outB[(size_t)row * N + col] = f2b(acc[i][j][r]);
      }
    }
  }
}

// ---------------------------------------------------------------------------
// Flash attention, transposed-output scheme.
// Per wave: 64 q-rows. S^T = K·Q^T (C cols = q = lane&15 -> softmax lane-local).
// P staged per-wave in LDS (row stride 40 ushorts = 80B -> <=2-way banks).
// out^T = V^T·P^T with A-frags straight from vt (contiguous 16B).
__global__ __launch_bounds__(256, 2) void attn_k(
    const unsigned short* __restrict__ qkv, const unsigned short* __restrict__ vt,
    unsigned short* __restrict__ ao) {
  __shared__ unsigned short Pl[4][64 * 40];
  const int tid = threadIdx.x;
  const int lane = tid & 63;
  const int wv = tid >> 6;
  const int bh = blockIdx.x;
  const int b = bh >> 4, h = bh & 15;
  const int q0 = blockIdx.y * 256 + wv * 64;
  const int fr = lane & 15;
  const int g8 = (lane >> 4) * 8;
  const int g4 = (lane >> 4) * 4;
  const float CSC = 0.125f * 1.44269504f;  // head-scale * log2(e)

  // Q fragments (B-operand of S^T): held in registers for the whole kernel
  bf16x8 bq[4][2];
#pragma unroll
  for (int qt = 0; qt < 4; ++qt)
#pragma unroll
    for (int ks = 0; ks < 2; ++ks)
      bq[qt][ks] = *(const bf16x8*)&qkv[(size_t)(b * 2048 + q0 + qt * 16 + fr) * 3072 +
                                        h * 64 + ks * 32 + g8];

  f32x4 acc[4][4];  // out^T: [d-tile][q-tile]
#pragma unroll
  for (int i = 0; i < 4; ++i)
#pragma unroll
    for (int j = 0; j < 4; ++j) acc[i][j] = (f32x4){0.f, 0.f, 0.f, 0.f};
  float m[4], l[4];
#pragma unroll
  for (int qt = 0; qt < 4; ++qt) { m[qt] = -1e30f; l[qt] = 0.f; }

  const size_t krow = (size_t)(b * 2048) * 3072 + 1024 + h * 64;
  const size_t vrow = (size_t)(bh * 64) * 2048;

  for (int kt = 0; kt < 64; ++kt) {
    const int key0 = kt * 32;
    // K fragments (A-operand), straight from global (L2/L3-resident)
    bf16x8 ak[2][2];
#pragma unroll
    for (int kk = 0; kk < 2; ++kk)
#pragma unroll
      for (int ks = 0; ks < 2; ++ks)
        ak[kk][ks] = *(const bf16x8*)&qkv[krow + (size_t)(key0 + kk * 16 + fr) * 3072 +
                                          ks * 32 + g8];
    // S^T = K · Q^T
    f32x4 st[2][4];
#pragma unroll
    for (int kk = 0; kk < 2; ++kk)
#pragma unroll
      for (int qt = 0; qt < 4; ++qt) {
        f32x4 z = (f32x4){0.f, 0.f, 0.f, 0.f};
        z = __builtin_amdgcn_mfma_f32_16x16x32_bf16(ak[kk][0], bq[qt][0], z, 0, 0, 0);
        st[kk][qt] = __builtin_amdgcn_mfma_f32_16x16x32_bf16(ak[kk][1], bq[qt][1], z, 0, 0, 0);
      }
    // online softmax (per qt; q = qt*16 + (lane&15), all stats lane-local)
#pragma unroll
    for (int qt = 0; qt < 4; ++qt) {
      float t0 = fmaxf(fmaxf(st[0][qt][0], st[0][qt][1]), fmaxf(st[0][qt][2], st[0][qt][3]));
      float t1 = fmaxf(fmaxf(st[1][qt][0], st[1][qt][1]), fmaxf(st[1][qt][2], st[1][qt][3]));
      float tm = fmaxf(t0, t1);
      tm = fmaxf(tm, __shfl_xor(tm, 16, 64));
      tm = fmaxf(tm, __shfl_xor(tm, 32, 64));
      const float mold = m[qt];
      const float mnew = fmaxf(mold, tm);
      const float corr = exp2f((mold - mnew) * CSC);
      const float mc = mnew * CSC;
      float p0 = exp2f(st[0][qt][0] * CSC - mc);
      float p1 = exp2f(st[0][qt][1] * CSC - mc);
      float p2 = exp2f(st[0][qt][2] * CSC - mc);
      float p3 = exp2f(st[0][qt][3] * CSC - mc);
      float p4 = exp2f(st[1][qt][0] * CSC - mc);
      float p5 = exp2f(st[1][qt][1] * CSC - mc);
      float p6 = exp2f(st[1][qt][2] * CSC - mc);
      float p7 = exp2f(st[1][qt][3] * CSC - mc);
      float rs = ((p0 + p1) + (p2 + p3)) + ((p4 + p5) + (p6 + p7));
      rs += __shfl_xor(rs, 16, 64);
      rs += __shfl_xor(rs, 32, 64);
      l[qt] = l[qt] * corr + rs;
      m[qt] = mnew;
#pragma unroll
      for (int dt = 0; dt < 4; ++dt) {
        acc[dt][qt][0] *= corr; acc[dt][qt][1] *= corr;
        acc[dt][qt][2] *= corr; acc[dt][qt][3] *= corr;
      }
      *(ushort4*)&Pl[wv][(qt * 16 + fr) * 40 + g4]      = make_ushort4(f2b(p0), f2b(p1), f2b(p2), f2b(p3));
      *(ushort4*)&Pl[wv][(qt * 16 + fr) * 40 + 16 + g4] = make_ushort4(f2b(p4), f2b(p5), f2b(p6), f2b(p7));
    }
    // PV: out^T += V^T · P^T
    bf16x8 av[4], bp[4];
#pragma unroll
    for (int dt = 0; dt < 4; ++dt)
      av[dt] = *(const bf16x8*)&vt[vrow + (size_t)(dt * 16 + fr) * 2048 + key0 + g8];
#pragma unroll
    for (int qt = 0; qt < 4; ++qt)
      bp[qt] = *(const bf16x8*)&Pl[wv][(qt * 16 + fr) * 40 + g8];
#pragma unroll
    for (int dt = 0; dt < 4; ++dt)
#pragma unroll
      for (int qt = 0; qt < 4; ++qt)
        acc[dt][qt] = __builtin_amdgcn_mfma_f32_16x16x32_bf16(av[dt], bp[qt], acc[dt][qt], 0, 0, 0);
  }
  // normalize + store (bf16, [b*2048+n][h*64+d])
#pragma unroll
  for (int qt = 0; qt < 4; ++qt) {
    const float inv = 1.0f / l[qt];
#pragma unroll
    for (int dt = 0; dt < 4; ++dt) {
      ushort4 o = make_ushort4(f2b(acc[dt][qt][0] * inv), f2b(acc[dt][qt][1] * inv),
                               f2b(acc[dt][qt][2] * inv), f2b(acc[dt][qt][3] * inv));
      *(ushort4*)&ao[(size_t)(b * 2048 + q0 + qt * 16 + fr) * 1024 + h * 64 + dt * 16 + g4] = o;
    }
  }
}

// ---------------------------------------------------------------------------
extern "C" void kernel_launch(void* const* d_in, const int* in_sizes, int n_in,
                              void* d_out, int out_size, void* d_ws, size_t ws_size,
                              hipStream_t stream) {
  const float* x     = (const float*)d_in[0];
  const float* wqkv  = (const float*)d_in[1];
  const float* wproj = (const float*)d_in[2];
  const float* bproj = (const float*)d_in[3];
  float* out = (float*)d_out;
  char* ws = (char*)d_ws;

  // workspace layout (bytes)
  unsigned short* xb     = (unsigned short*)(ws + 0);          // 16.78 MB
  unsigned short* wqkvT  = (unsigned short*)(ws + 16777216);   //  6.29 MB
  unsigned short* wprojT = (unsigned short*)(ws + 23068672);   //  2.10 MB
  unsigned short* qkv    = (unsigned short*)(ws + 25165824);   // 50.33 MB
  unsigned short* vt     = (unsigned short*)(ws + 75497472);   // 16.78 MB
  unsigned short* ao     = (unsigned short*)(ws + 92274688);   // 16.78 MB

  k_cvt<<<8192, 256, 0, stream>>>(x, xb);
  k_wt<<<dim3(48, 16), dim3(64, 4), 0, stream>>>(wqkv, wqkvT, 3072, 1024);
  k_wt<<<dim3(16, 16), dim3(64, 4), 0, stream>>>(wproj, wprojT, 1024, 1024);
  gemm_bt<false><<<dim3(24, 64), 256, 0, stream>>>(xb, wqkvT, qkv, nullptr, nullptr,
                                                   8192, 3072, 1024);
  k_vt<<<dim3(32, 64), dim3(64, 4), 0, stream>>>(qkv, vt);
  attn_k<<<dim3(64, 8), 256, 0, stream>>>(qkv, vt, ao);
  gemm_bt<true><<<dim3(8, 64), 256, 0, stream>>>(ao, wprojT, nullptr, out, bproj,
                                                 8192, 1024, 1024);
}